// Round 1
// baseline (965.279 us; speedup 1.0000x reference)
//
#include <hip/hip_runtime.h>
#include <math.h>

// ProteinMPNN layer forward, fp32 baseline.
// B=2 N=2048 K=48 H=128 FF=512. Compute-bound (~39 GF fp32 after the
// W1-split precompute trick). Per-node fused 3-layer MLP kernels with
// LDS-chunked weights; separate small kernels for projections and FFN.

#define Bn 2
#define Nn 2048
#define Kn 48
#define Hn 128
#define FFn 512
#define PAD 132
#define CH 16

__device__ __forceinline__ float gelu_f(float x){
    return 0.5f * x * (1.0f + erff(x * 0.70710678118654752440f));
}

__device__ __forceinline__ float4 f4add(float4 a, float4 b){
    return make_float4(a.x+b.x, a.y+b.y, a.z+b.z, a.w+b.w);
}
__device__ __forceinline__ float4 fma4(float s, float4 w, float4 a){
    a.x = fmaf(s, w.x, a.x); a.y = fmaf(s, w.y, a.y);
    a.z = fmaf(s, w.z, a.z); a.w = fmaf(s, w.w, a.w);
    return a;
}
__device__ __forceinline__ float4 gelu4(float4 a){
    return make_float4(gelu_f(a.x), gelu_f(a.y), gelu_f(a.z), gelu_f(a.w));
}

// ---------------------------------------------------------------------------
// proj_kernel: A_self[node] = h_V[node] @ W[0:H] + bias ; A_nb = h_V @ W[2H:3H]
// grid = B*N blocks, 256 threads (t<128 -> self, t>=128 -> nb)
// ---------------------------------------------------------------------------
__global__ __launch_bounds__(256) void proj_kernel(
    const float* __restrict__ hv, const float* __restrict__ W,
    const float* __restrict__ bias,
    float* __restrict__ Aself, float* __restrict__ Anb)
{
    __shared__ float xs[Hn];
    const int t = threadIdx.x;
    const int node = blockIdx.x;
    if (t < Hn) xs[t] = hv[(size_t)node*Hn + t];
    __syncthreads();
    const int o = t & (Hn-1);
    const bool self = (t < Hn);
    const float* Wp = W + (self ? 0 : 2*Hn)*Hn + o;
    float acc = self ? bias[o] : 0.0f;
    #pragma unroll 4
    for (int i = 0; i < Hn; ++i) acc = fmaf(xs[i], Wp[i*Hn], acc);
    if (self) Aself[(size_t)node*Hn + o] = acc;
    else      Anb[(size_t)node*Hn + o]  = acc;
}

// ---------------------------------------------------------------------------
// mm128: acc[6 k][4 o] += Xin[48][128] @ Wg[128][128], weights chunked via LDS.
// Two barriers per chunk make the Ws overwrite safe.
// ---------------------------------------------------------------------------
__device__ __forceinline__ void mm128(
    const float (*Xin)[PAD], float (*Ws)[PAD], const float* __restrict__ Wg,
    float4 acc[6], int kg, int o4, int t)
{
    for (int c0 = 0; c0 < Hn; c0 += CH){
        __syncthreads();               // prev chunk fully consumed / Xin ready
        {
            const int cr  = t >> 4;            // 0..15
            const int col = (t & 15) * 8;      // 0..120
            const float* src = Wg + (c0 + cr)*Hn + col;
            float4 a = *(const float4*)(src);
            float4 b = *(const float4*)(src + 4);
            *(float4*)&Ws[cr][col]     = a;
            *(float4*)&Ws[cr][col + 4] = b;
        }
        __syncthreads();
        #pragma unroll
        for (int i4 = 0; i4 < CH; i4 += 4){
            float4 w0 = *(const float4*)&Ws[i4+0][o4];
            float4 w1 = *(const float4*)&Ws[i4+1][o4];
            float4 w2 = *(const float4*)&Ws[i4+2][o4];
            float4 w3 = *(const float4*)&Ws[i4+3][o4];
            #pragma unroll
            for (int j = 0; j < 6; ++j){
                float4 x = *(const float4*)&Xin[kg*6 + j][c0 + i4];
                acc[j] = fma4(x.x, w0, acc[j]);
                acc[j] = fma4(x.y, w1, acc[j]);
                acc[j] = fma4(x.z, w2, acc[j]);
                acc[j] = fma4(x.w, w3, acc[j]);
            }
        }
    }
}

// ---------------------------------------------------------------------------
// msg_node_kernel: node-message block. One block per node (48 edges).
// y = MLP3(h_E@Wmid + A_self + A_nb[idx]); dh = sum_k mask*y/30;
// hVa = LN(h_V + dh)
// ---------------------------------------------------------------------------
__global__ __launch_bounds__(256,2) void msg_node_kernel(
    const float* __restrict__ hV, const float* __restrict__ hE,
    const int* __restrict__ Eidx, const float* __restrict__ maskA,
    const float* __restrict__ Aself, const float* __restrict__ Anb,
    const float* __restrict__ Wmid,
    const float* __restrict__ W2, const float* __restrict__ b2,
    const float* __restrict__ W3, const float* __restrict__ b3,
    const float* __restrict__ g1, const float* __restrict__ be1,
    float* __restrict__ hVa)
{
    __shared__ float Xs[Kn][PAD];
    __shared__ float Ys[Kn][PAD];
    __shared__ float Ws[CH][PAD];
    const int t = threadIdx.x;
    const int node = blockIdx.x;
    const int b = node >> 11;            // node / N
    const int o4 = (t & 31) * 4;
    const int kg = t >> 5;               // 0..7, owns k = kg*6 + j

    // stage h_E tile into LDS
    const float* hEn = hE + (size_t)node * Kn * Hn;
    #pragma unroll
    for (int it = 0; it < (Kn*Hn)/(256*4); ++it){
        int idx = (t + it*256) * 4;
        int k = idx >> 7, c = idx & (Hn-1);
        *(float4*)&Xs[k][c] = *(const float4*)&hEn[idx];
    }

    int myk[6];
    #pragma unroll
    for (int j = 0; j < 6; ++j) myk[j] = Eidx[(size_t)node*Kn + kg*6 + j];

    float4 acc[6];
    {
        float4 aself = *(const float4*)&Aself[(size_t)node*Hn + o4];
        #pragma unroll
        for (int j = 0; j < 6; ++j){
            float4 anb = *(const float4*)&Anb[((size_t)b*Nn + myk[j])*Hn + o4];
            acc[j] = f4add(aself, anb);
        }
    }
    // layer 1
    mm128(Xs, Ws, Wmid, acc, kg, o4, t);
    #pragma unroll
    for (int j = 0; j < 6; ++j) *(float4*)&Ys[kg*6 + j][o4] = gelu4(acc[j]);
    // layer 2
    {
        float4 bb = *(const float4*)&b2[o4];
        #pragma unroll
        for (int j = 0; j < 6; ++j) acc[j] = bb;
    }
    mm128(Ys, Ws, W2, acc, kg, o4, t);
    #pragma unroll
    for (int j = 0; j < 6; ++j) *(float4*)&Xs[kg*6 + j][o4] = gelu4(acc[j]);
    // layer 3
    {
        float4 bb = *(const float4*)&b3[o4];
        #pragma unroll
        for (int j = 0; j < 6; ++j) acc[j] = bb;
    }
    mm128(Xs, Ws, W3, acc, kg, o4, t);

    // mask + per-thread k-sum
    float4 part = make_float4(0.f, 0.f, 0.f, 0.f);
    #pragma unroll
    for (int j = 0; j < 6; ++j){
        float m = maskA[(size_t)node*Kn + kg*6 + j];
        part = fma4(m, acc[j], part);
    }
    __syncthreads();                 // all threads done reading Ws
    *(float4*)&Ws[kg][o4] = part;    // red[8][128] overlay
    __syncthreads();
    if (t < 32){
        float4 s = make_float4(0.f, 0.f, 0.f, 0.f);
        #pragma unroll
        for (int g = 0; g < 8; ++g) s = f4add(s, *(const float4*)&Ws[g][t*4]);
        const float inv30 = 1.0f / 30.0f;
        float4 hv = *(const float4*)&hV[(size_t)node*Hn + t*4];
        float4 v = make_float4(hv.x + s.x*inv30, hv.y + s.y*inv30,
                               hv.z + s.z*inv30, hv.w + s.w*inv30);
        float ls = v.x + v.y + v.z + v.w;
        #pragma unroll
        for (int off = 16; off; off >>= 1) ls += __shfl_xor(ls, off);
        float mean = ls * (1.0f/128.0f);
        float4 d = make_float4(v.x-mean, v.y-mean, v.z-mean, v.w-mean);
        float ls2 = d.x*d.x + d.y*d.y + d.z*d.z + d.w*d.w;
        #pragma unroll
        for (int off = 16; off; off >>= 1) ls2 += __shfl_xor(ls2, off);
        float invs = rsqrtf(ls2 * (1.0f/128.0f) + 1e-5f);
        float4 gg = *(const float4*)&g1[t*4];
        float4 bb = *(const float4*)&be1[t*4];
        float4 o = make_float4(d.x*invs*gg.x + bb.x, d.y*invs*gg.y + bb.y,
                               d.z*invs*gg.z + bb.z, d.w*invs*gg.w + bb.w);
        *(float4*)&hVa[(size_t)node*Hn + t*4] = o;
    }
}

// ---------------------------------------------------------------------------
// ffn_kernel: hVout = mask_V * LN(hVa + gelu(hVa@Wi+bi)@Wo + bo)
// ---------------------------------------------------------------------------
__global__ __launch_bounds__(256) void ffn_kernel(
    const float* __restrict__ hVa,
    const float* __restrict__ Wi, const float* __restrict__ bi,
    const float* __restrict__ Wo, const float* __restrict__ bo,
    const float* __restrict__ g2, const float* __restrict__ be2,
    const float* __restrict__ maskV, float* __restrict__ hVout)
{
    __shared__ float xs[Hn];
    __shared__ float us[FFn];
    __shared__ float wr1[4], wr2[4];
    const int t = threadIdx.x;
    const int node = blockIdx.x;
    if (t < Hn) xs[t] = hVa[(size_t)node*Hn + t];
    __syncthreads();
    #pragma unroll
    for (int o = t; o < FFn; o += 256){
        float a = bi[o];
        #pragma unroll 4
        for (int i = 0; i < Hn; ++i) a = fmaf(xs[i], Wi[i*FFn + o], a);
        us[o] = gelu_f(a);
    }
    __syncthreads();
    float tv = 0.0f;
    if (t < Hn){
        float a = bo[t];
        #pragma unroll 4
        for (int j = 0; j < FFn; ++j) a = fmaf(us[j], Wo[j*Hn + t], a);
        tv = xs[t] + a;
    }
    float ls = tv;
    #pragma unroll
    for (int off = 32; off; off >>= 1) ls += __shfl_xor(ls, off);
    if ((t & 63) == 0) wr1[t >> 6] = ls;
    __syncthreads();
    float mean = (wr1[0] + wr1[1] + wr1[2] + wr1[3]) * (1.0f/128.0f);
    float d = (t < Hn) ? (tv - mean) : 0.0f;
    float ls2 = d * d;
    #pragma unroll
    for (int off = 32; off; off >>= 1) ls2 += __shfl_xor(ls2, off);
    if ((t & 63) == 0) wr2[t >> 6] = ls2;
    __syncthreads();
    float invs = rsqrtf((wr2[0] + wr2[1] + wr2[2] + wr2[3]) * (1.0f/128.0f) + 1e-5f);
    if (t < Hn){
        float y = d * invs * g2[t] + be2[t];
        hVout[(size_t)node*Hn + t] = maskV[node] * y;
    }
}

// ---------------------------------------------------------------------------
// msg_edge_kernel: edge-message block. hE_out = LN(h_E + MLP3(...), g3, be3)
// ---------------------------------------------------------------------------
__global__ __launch_bounds__(256,2) void msg_edge_kernel(
    const float* __restrict__ hE, const int* __restrict__ Eidx,
    const float* __restrict__ Bself, const float* __restrict__ Bnb,
    const float* __restrict__ Wmid,
    const float* __restrict__ W2, const float* __restrict__ b2,
    const float* __restrict__ W3, const float* __restrict__ b3,
    const float* __restrict__ g3, const float* __restrict__ be3,
    float* __restrict__ outE)
{
    __shared__ float Xs[Kn][PAD];
    __shared__ float Ys[Kn][PAD];
    __shared__ float Ws[CH][PAD];
    const int t = threadIdx.x;
    const int node = blockIdx.x;
    const int b = node >> 11;
    const int o4 = (t & 31) * 4;
    const int kg = t >> 5;

    const float* hEn = hE + (size_t)node * Kn * Hn;
    #pragma unroll
    for (int it = 0; it < (Kn*Hn)/(256*4); ++it){
        int idx = (t + it*256) * 4;
        int k = idx >> 7, c = idx & (Hn-1);
        *(float4*)&Xs[k][c] = *(const float4*)&hEn[idx];
    }
    int myk[6];
    #pragma unroll
    for (int j = 0; j < 6; ++j) myk[j] = Eidx[(size_t)node*Kn + kg*6 + j];

    float4 acc[6];
    {
        float4 bself = *(const float4*)&Bself[(size_t)node*Hn + o4];
        #pragma unroll
        for (int j = 0; j < 6; ++j){
            float4 bnb = *(const float4*)&Bnb[((size_t)b*Nn + myk[j])*Hn + o4];
            acc[j] = f4add(bself, bnb);
        }
    }
    mm128(Xs, Ws, Wmid, acc, kg, o4, t);
    #pragma unroll
    for (int j = 0; j < 6; ++j) *(float4*)&Ys[kg*6 + j][o4] = gelu4(acc[j]);
    {
        float4 bb = *(const float4*)&b2[o4];
        #pragma unroll
        for (int j = 0; j < 6; ++j) acc[j] = bb;
    }
    mm128(Ys, Ws, W2, acc, kg, o4, t);
    #pragma unroll
    for (int j = 0; j < 6; ++j) *(float4*)&Xs[kg*6 + j][o4] = gelu4(acc[j]);
    {
        float4 bb = *(const float4*)&b3[o4];
        #pragma unroll
        for (int j = 0; j < 6; ++j) acc[j] = bb;
    }
    mm128(Xs, Ws, W3, acc, kg, o4, t);

    // park y3 in Ys, then per-edge-row LayerNorm (4 threads per row)
    __syncthreads();
    #pragma unroll
    for (int j = 0; j < 6; ++j) *(float4*)&Ys[kg*6 + j][o4] = acc[j];
    __syncthreads();

    const int r = t >> 2, c = t & 3;
    if (r < Kn){
        float4 v[8];
        float ls = 0.0f;
        #pragma unroll
        for (int m = 0; m < 8; ++m){
            float4 y = *(const float4*)&Ys[r][c*32 + m*4];
            float4 e = *(const float4*)&hEn[r*Hn + c*32 + m*4];
            v[m] = f4add(y, e);
            ls += v[m].x + v[m].y + v[m].z + v[m].w;
        }
        ls += __shfl_xor(ls, 1);
        ls += __shfl_xor(ls, 2);
        float mean = ls * (1.0f/128.0f);
        float ls2 = 0.0f;
        #pragma unroll
        for (int m = 0; m < 8; ++m){
            float4 d = make_float4(v[m].x-mean, v[m].y-mean, v[m].z-mean, v[m].w-mean);
            ls2 += d.x*d.x + d.y*d.y + d.z*d.z + d.w*d.w;
        }
        ls2 += __shfl_xor(ls2, 1);
        ls2 += __shfl_xor(ls2, 2);
        float invs = rsqrtf(ls2 * (1.0f/128.0f) + 1e-5f);
        float* outR = outE + (size_t)node*Kn*Hn + r*Hn + c*32;
        #pragma unroll
        for (int m = 0; m < 8; ++m){
            float4 gg = *(const float4*)&g3[c*32 + m*4];
            float4 bb = *(const float4*)&be3[c*32 + m*4];
            float4 o = make_float4((v[m].x-mean)*invs*gg.x + bb.x,
                                   (v[m].y-mean)*invs*gg.y + bb.y,
                                   (v[m].z-mean)*invs*gg.z + bb.z,
                                   (v[m].w-mean)*invs*gg.w + bb.w);
            *(float4*)&outR[m*4] = o;
        }
    }
}

// ---------------------------------------------------------------------------
extern "C" void kernel_launch(void* const* d_in, const int* in_sizes, int n_in,
                              void* d_out, int out_size, void* d_ws, size_t ws_size,
                              hipStream_t stream)
{
    const float* h_V  = (const float*)d_in[0];
    const float* h_E  = (const float*)d_in[1];
    const int*   E_idx = (const int*)d_in[2];
    const float* mask_V = (const float*)d_in[3];
    const float* mask_attend = (const float*)d_in[4];
    const float* W1 = (const float*)d_in[5];  const float* b1 = (const float*)d_in[6];
    const float* W2 = (const float*)d_in[7];  const float* b2 = (const float*)d_in[8];
    const float* W3 = (const float*)d_in[9];  const float* b3 = (const float*)d_in[10];
    const float* W11 = (const float*)d_in[11]; const float* b11 = (const float*)d_in[12];
    const float* W12 = (const float*)d_in[13]; const float* b12 = (const float*)d_in[14];
    const float* W13 = (const float*)d_in[15]; const float* b13 = (const float*)d_in[16];
    const float* Wi = (const float*)d_in[17]; const float* bi = (const float*)d_in[18];
    const float* Wo = (const float*)d_in[19]; const float* bo = (const float*)d_in[20];
    const float* g1 = (const float*)d_in[21]; const float* be1 = (const float*)d_in[22];
    const float* g2 = (const float*)d_in[23]; const float* be2 = (const float*)d_in[24];
    const float* g3 = (const float*)d_in[25]; const float* be3 = (const float*)d_in[26];

    const size_t BN = (size_t)Bn * Nn;
    float* Aself = (float*)d_ws;               // [B*N, H]
    float* Anb   = Aself + BN * Hn;            // [B*N, H]
    float* hVa   = Anb + BN * Hn;              // [B*N, H]
    float* hVout = (float*)d_out;              // [B*N, H]
    float* hEout = hVout + BN * Hn;            // [B*N, K, H]

    dim3 grid(Bn * Nn), blk(256);
    // node-message block
    proj_kernel<<<grid, blk, 0, stream>>>(h_V, W1, b1, Aself, Anb);
    msg_node_kernel<<<grid, blk, 0, stream>>>(h_V, h_E, E_idx, mask_attend,
        Aself, Anb, W1 + Hn*Hn, W2, b2, W3, b3, g1, be1, hVa);
    // position-wise FFN
    ffn_kernel<<<grid, blk, 0, stream>>>(hVa, Wi, bi, Wo, bo, g2, be2, mask_V, hVout);
    // edge-message block (uses updated, masked h_V)
    proj_kernel<<<grid, blk, 0, stream>>>(hVout, W11, b11, Aself, Anb);
    msg_edge_kernel<<<grid, blk, 0, stream>>>(h_E, E_idx, Aself, Anb,
        W11 + Hn*Hn, W12, b12, W13, b13, g3, be3, hEout);
}

// Round 6
// 515.343 us; speedup vs baseline: 1.8731x; 1.8731x over previous
//
#include <hip/hip_runtime.h>
#include <math.h>

// ProteinMPNN layer forward, split-bf16 MFMA version.
// B=2 N=2048 K=48 H=128 FF=512.
// Matmuls on v_mfma_f32_16x16x32_bf16 with hi/lo split (3 MFMAs per product
// pair -> ~fp32 accuracy). Weights pre-packed per launch into fragment order
// (hi/lo bf16) in d_ws. X tiles live in LDS f32 with chunk-XOR swizzle
// (chunk ^= row&7) so fragment reads and LN-epilogue reads are ~2-way max.
// hVa intermediate lives in d_out's hEout region (dead before msg_edge
// writes it) to keep d_ws usage within the proven >=6.3MB budget.

#define Bn 2
#define Nn 2048
#define Kn 48
#define Hn 128
#define FFn 512

typedef __attribute__((ext_vector_type(8))) short short8;
typedef __attribute__((ext_vector_type(4))) float f32x4;

__device__ __forceinline__ float gelu_f(float x){
    return 0.5f * x * (1.0f + erff(x * 0.70710678118654752440f));
}

__device__ __forceinline__ unsigned short rne_bf16(float x){
    unsigned int b = __float_as_uint(x);
    return (unsigned short)((b + 0x7fffu + ((b >> 16) & 1u)) >> 16);
}

// split 8 f32 -> hi/lo bf16 fragments (k-contiguous per lane)
__device__ __forceinline__ void split8(const float* x, short8& h, short8& l){
    #pragma unroll
    for (int i = 0; i < 8; ++i){
        unsigned short hu = rne_bf16(x[i]);
        float hf = __uint_as_float(((unsigned int)hu) << 16);
        float r = x[i] - hf;
        h[i] = (short)hu;
        l[i] = (short)rne_bf16(r);
    }
}

// swizzled f32 LDS index for a [rows][128] tile (row stride 512B):
// 16B chunk index XOR'd with row&7 -> fragment reads spread over 8 bank-quads
__device__ __forceinline__ int xaddr(int row, int col){
    int chunk = (col >> 2) ^ (row & 7);
    return row * 128 + chunk * 4 + (col & 3);
}
// same for [rows][512] tile (row stride 2048B)
__device__ __forceinline__ int x1addr(int row, int col){
    int chunk = (col >> 2) ^ (row & 7);
    return row * 512 + chunk * 4 + (col & 3);
}

// ---------------------------------------------------------------------------
// pack_kernel: W (K x N f32 row-major) -> fragment-ordered hi/lo bf16.
// Work item lf = fs*64+lane, fs = nt*KS + ks; elem i =
// W[ks*32+(lane>>4)*8+i][nt*16+(lane&15)].
// Regions (short offsets): 6x 128x128 (hi 16384 + lo 16384 each),
// Wi 128x512 @196608, Wo 512x128 @327680. Total 458752 shorts = 896KB.
// ---------------------------------------------------------------------------
__global__ __launch_bounds__(256) void pack_kernel(
    const float* __restrict__ W1, const float* __restrict__ W2,
    const float* __restrict__ W3, const float* __restrict__ W11,
    const float* __restrict__ W12, const float* __restrict__ W13,
    const float* __restrict__ Wi, const float* __restrict__ Wo,
    short* __restrict__ out)
{
    int fid = blockIdx.x * 256 + threadIdx.x;   // grid = 112*256 = 28672 exact
    const float* W; int N, KS, fb, nf; size_t hb;
    if (fid < 12288){
        int r = fid >> 11;                       // 0..5
        if      (r == 0) W = W1 + Hn * Hn;       // W1 middle slice (h_E part)
        else if (r == 1) W = W2;
        else if (r == 2) W = W3;
        else if (r == 3) W = W11 + Hn * Hn;
        else if (r == 4) W = W12;
        else             W = W13;
        N = 128; KS = 4; fb = r << 11; nf = 2048; hb = (size_t)r * 32768;
    } else if (fid < 20480){
        W = Wi; N = 512; KS = 4; fb = 12288; nf = 8192; hb = 196608;
    } else {
        W = Wo; N = 128; KS = 16; fb = 20480; nf = 8192; hb = 327680;
    }
    int lf = fid - fb;
    int lane = lf & 63;
    int fs = lf >> 6;
    int ks = fs % KS;
    int nt = fs / KS;
    int k0 = ks * 32 + ((lane >> 4) << 3);
    int col = nt * 16 + (lane & 15);
    float xv[8];
    #pragma unroll
    for (int i = 0; i < 8; ++i) xv[i] = W[(size_t)(k0 + i) * N + col];
    short8 h8, l8;
    split8(xv, h8, l8);
    *(short8*)(out + hb + (size_t)lf * 8) = h8;
    *(short8*)(out + hb + (size_t)nf * 8 + (size_t)lf * 8) = l8;
}

// ---------------------------------------------------------------------------
// proj_kernel: A_self[node] = h_V[node] @ W[0:H] + bias ; A_nb = h_V @ W[2H:3H]
// (fp32 VALU; small)
// ---------------------------------------------------------------------------
__global__ __launch_bounds__(256) void proj_kernel(
    const float* __restrict__ hv, const float* __restrict__ W,
    const float* __restrict__ bias,
    float* __restrict__ Aself, float* __restrict__ Anb)
{
    __shared__ float xs[Hn];
    const int t = threadIdx.x;
    const int node = blockIdx.x;
    if (t < Hn) xs[t] = hv[(size_t)node*Hn + t];
    __syncthreads();
    const int o = t & (Hn-1);
    const bool self = (t < Hn);
    const float* Wp = W + (self ? 0 : 2*Hn)*Hn + o;
    float acc = self ? bias[o] : 0.0f;
    #pragma unroll 4
    for (int i = 0; i < Hn; ++i) acc = fmaf(xs[i], Wp[i*Hn], acc);
    if (self) Aself[(size_t)node*Hn + o] = acc;
    else      Anb[(size_t)node*Hn + o]  = acc;
}

// ---------------------------------------------------------------------------
// msg_kernel<EDGE>: one block per node. 4 waves; wave w owns N-cols [32w,32w+32).
// X = 48x128 in swizzled LDS f32. 3 layers, each: MFMA (split-bf16) + epilogue.
// EDGE=0: mask+k-sum+LN -> hVa[node].  EDGE=1: per-edge LN -> hEout.
// ---------------------------------------------------------------------------
template<int EDGE>
__global__ __launch_bounds__(256,4) void msg_kernel(
    const float* __restrict__ hV, const float* __restrict__ hE,
    const int* __restrict__ Eidx, const float* __restrict__ maskA,
    const float* __restrict__ Aself, const float* __restrict__ Anb,
    const short* __restrict__ p1, const short* __restrict__ p2,
    const short* __restrict__ p3,
    const float* __restrict__ b2v, const float* __restrict__ b3v,
    const float* __restrict__ g, const float* __restrict__ be,
    float* __restrict__ out)
{
    __shared__ float Xs[Kn * Hn];     // 24 KB, swizzled
    __shared__ float dhs[Hn];
    const int t = threadIdx.x;
    const int node = blockIdx.x;
    const int b = node >> 11;
    const int w = t >> 6, l = t & 63;
    const int l15 = l & 15, lg = l >> 4;

    // stage h_E -> Xs (swizzled)
    const float* hEn = hE + (size_t)node * Kn * Hn;
    #pragma unroll
    for (int it = 0; it < 6; ++it){
        int idx = (t + it*256) * 4;
        int r = idx >> 7, c = idx & 127;
        *(f32x4*)&Xs[xaddr(r, c)] = *(const f32x4*)&hEn[idx];
    }

    // layer-1 acc init: Aself (bias folded) + Anb[gather]
    f32x4 acc[3][2];
    {
        int c0 = (2*w)*16 + l15;
        float as0 = Aself[(size_t)node*Hn + c0];
        float as1 = Aself[(size_t)node*Hn + c0 + 16];
        #pragma unroll
        for (int mt = 0; mt < 3; ++mt){
            #pragma unroll
            for (int rr = 0; rr < 4; ++rr){
                int row = mt*16 + lg*4 + rr;
                int idx = Eidx[(size_t)node*Kn + row];
                const float* an = Anb + ((size_t)(b*Nn + idx))*Hn;
                acc[mt][0][rr] = as0 + an[c0];
                acc[mt][1][rr] = as1 + an[c0 + 16];
            }
        }
    }
    __syncthreads();

    #pragma unroll
    for (int L = 0; L < 3; ++L){
        const short* ph = (L == 0) ? p1 : (L == 1) ? p2 : p3;
        if (L > 0){
            const float* bv = (L == 1) ? b2v : b3v;
            int c0 = (2*w)*16 + l15;
            float v0 = bv[c0], v1 = bv[c0 + 16];
            #pragma unroll
            for (int mt = 0; mt < 3; ++mt)
                #pragma unroll
                for (int rr = 0; rr < 4; ++rr){
                    acc[mt][0][rr] = v0; acc[mt][1][rr] = v1;
                }
        }
        #pragma unroll
        for (int ks = 0; ks < 4; ++ks){
            short8 ah[3], al[3];
            #pragma unroll
            for (int mt = 0; mt < 3; ++mt){
                int row = mt*16 + l15;
                int c0 = (ks*32 + lg*8) >> 2;
                f32x4 xa = *(const f32x4*)&Xs[row*128 + (( c0    ^ (row&7)) << 2)];
                f32x4 xb = *(const f32x4*)&Xs[row*128 + (((c0+1) ^ (row&7)) << 2)];
                float xv[8] = {xa[0],xa[1],xa[2],xa[3],xb[0],xb[1],xb[2],xb[3]};
                split8(xv, ah[mt], al[mt]);
            }
            #pragma unroll
            for (int ntl = 0; ntl < 2; ++ntl){
                int nt = 2*w + ntl;
                size_t f = ((size_t)(nt*4 + ks)*64 + l)*8;
                short8 bh = *(const short8*)(ph + f);
                short8 bl = *(const short8*)(ph + 16384 + f);
                #pragma unroll
                for (int mt = 0; mt < 3; ++mt){
                    acc[mt][ntl] = __builtin_amdgcn_mfma_f32_16x16x32_bf16(ah[mt], bh, acc[mt][ntl], 0,0,0);
                    acc[mt][ntl] = __builtin_amdgcn_mfma_f32_16x16x32_bf16(ah[mt], bl, acc[mt][ntl], 0,0,0);
                    acc[mt][ntl] = __builtin_amdgcn_mfma_f32_16x16x32_bf16(al[mt], bh, acc[mt][ntl], 0,0,0);
                }
            }
        }
        __syncthreads();            // all waves done reading Xs
        if (L < 2){
            #pragma unroll
            for (int mt = 0; mt < 3; ++mt)
                #pragma unroll
                for (int ntl = 0; ntl < 2; ++ntl){
                    int col = (2*w + ntl)*16 + l15;
                    #pragma unroll
                    for (int rr = 0; rr < 4; ++rr){
                        int row = mt*16 + lg*4 + rr;
                        Xs[xaddr(row, col)] = gelu_f(acc[mt][ntl][rr]);
                    }
                }
            __syncthreads();
        }
    }

    if (!EDGE){
        // mask + k-sum (C rows live in lane-groups; reduce across lg via shfl)
        float s0 = 0.f, s1 = 0.f;
        #pragma unroll
        for (int mt = 0; mt < 3; ++mt)
            #pragma unroll
            for (int rr = 0; rr < 4; ++rr){
                int row = mt*16 + lg*4 + rr;
                float m = maskA[(size_t)node*Kn + row];
                s0 = fmaf(m, acc[mt][0][rr], s0);
                s1 = fmaf(m, acc[mt][1][rr], s1);
            }
        s0 += __shfl_xor(s0, 16); s0 += __shfl_xor(s0, 32);
        s1 += __shfl_xor(s1, 16); s1 += __shfl_xor(s1, 32);
        if (lg == 0){
            dhs[2*w*16 + l15]      = s0;
            dhs[2*w*16 + 16 + l15] = s1;
        }
        __syncthreads();
        if (t < 32){
            f32x4 s = *(const f32x4*)&dhs[t*4];
            f32x4 hv = *(const f32x4*)&hV[(size_t)node*Hn + t*4];
            const float inv30 = 1.0f/30.0f;
            f32x4 v = hv + s*inv30;
            float ls = v[0]+v[1]+v[2]+v[3];
            #pragma unroll
            for (int off = 16; off; off >>= 1) ls += __shfl_xor(ls, off);
            float mean = ls * (1.0f/128.0f);
            f32x4 d = v - mean;
            float ls2 = d[0]*d[0]+d[1]*d[1]+d[2]*d[2]+d[3]*d[3];
            #pragma unroll
            for (int off = 16; off; off >>= 1) ls2 += __shfl_xor(ls2, off);
            float invs = rsqrtf(ls2 * (1.0f/128.0f) + 1e-5f);
            f32x4 gg = *(const f32x4*)&g[t*4];
            f32x4 bb = *(const f32x4*)&be[t*4];
            f32x4 o = d*invs*gg + bb;
            *(f32x4*)&out[(size_t)node*Hn + t*4] = o;
        }
    } else {
        // park y3 in Xs (swizzled), then per-edge-row LN
        #pragma unroll
        for (int mt = 0; mt < 3; ++mt)
            #pragma unroll
            for (int ntl = 0; ntl < 2; ++ntl){
                int col = (2*w + ntl)*16 + l15;
                #pragma unroll
                for (int rr = 0; rr < 4; ++rr){
                    int row = mt*16 + lg*4 + rr;
                    Xs[xaddr(row, col)] = acc[mt][ntl][rr];
                }
            }
        __syncthreads();
        if (t < 192){
            const int r = t >> 2, c = t & 3;
            f32x4 v[8];
            float ls = 0.0f;
            #pragma unroll
            for (int m = 0; m < 8; ++m){
                int col = c*32 + m*4;
                f32x4 y = *(const f32x4*)&Xs[xaddr(r, col)];
                f32x4 e = *(const f32x4*)&hEn[r*Hn + col];
                v[m] = y + e;
                ls += v[m][0]+v[m][1]+v[m][2]+v[m][3];
            }
            ls += __shfl_xor(ls, 1);
            ls += __shfl_xor(ls, 2);
            float mean = ls * (1.0f/128.0f);
            float ls2 = 0.0f;
            #pragma unroll
            for (int m = 0; m < 8; ++m){
                f32x4 d = v[m] - mean;
                ls2 += d[0]*d[0]+d[1]*d[1]+d[2]*d[2]+d[3]*d[3];
            }
            ls2 += __shfl_xor(ls2, 1);
            ls2 += __shfl_xor(ls2, 2);
            float invs = rsqrtf(ls2 * (1.0f/128.0f) + 1e-5f);
            float* outR = out + (size_t)node*Kn*Hn + r*Hn;
            #pragma unroll
            for (int m = 0; m < 8; ++m){
                int col = c*32 + m*4;
                f32x4 gg = *(const f32x4*)&g[col];
                f32x4 bb = *(const f32x4*)&be[col];
                f32x4 o = (v[m] - mean)*invs*gg + bb;
                *(f32x4*)&outR[col] = o;
            }
        }
    }
}

// ---------------------------------------------------------------------------
// ffn_mfma: block = 16 nodes. GEMM1 16x128x512, gelu, GEMM2 16x512x128,
// residual + LN + mask_V. Split-bf16 MFMA, swizzled LDS.
// ---------------------------------------------------------------------------
__global__ __launch_bounds__(256,4) void ffn_mfma(
    const float* __restrict__ hVa,
    const short* __restrict__ pWi, const short* __restrict__ pWo,
    const float* __restrict__ bi, const float* __restrict__ bo,
    const float* __restrict__ g2, const float* __restrict__ be2,
    const float* __restrict__ maskV, float* __restrict__ hVout)
{
    __shared__ float X0[16 * 128];    // 8 KB
    __shared__ float X1[16 * 512];    // 32 KB
    const int t = threadIdx.x;
    const int blk = blockIdx.x;
    const int w = t >> 6, l = t & 63;
    const int l15 = l & 15, lg = l >> 4;

    const float* src = hVa + (size_t)blk * 16 * Hn;
    #pragma unroll
    for (int it = 0; it < 2; ++it){
        int idx = (t + it*256) * 4;
        int r = idx >> 7, c = idx & 127;
        *(f32x4*)&X0[xaddr(r, c)] = *(const f32x4*)&src[idx];
    }
    __syncthreads();

    // GEMM1: wave w -> ntiles w*8 .. w*8+7 (cols w*128 .. w*128+127)
    f32x4 acc1[8];
    #pragma unroll
    for (int ntl = 0; ntl < 8; ++ntl){
        float bb = bi[(w*8 + ntl)*16 + l15];
        acc1[ntl][0] = bb; acc1[ntl][1] = bb; acc1[ntl][2] = bb; acc1[ntl][3] = bb;
    }
    #pragma unroll
    for (int ks = 0; ks < 4; ++ks){
        int row = l15;
        int c0 = (ks*32 + lg*8) >> 2;
        f32x4 xa = *(const f32x4*)&X0[row*128 + (( c0    ^ (row&7)) << 2)];
        f32x4 xb = *(const f32x4*)&X0[row*128 + (((c0+1) ^ (row&7)) << 2)];
        float xv[8] = {xa[0],xa[1],xa[2],xa[3],xb[0],xb[1],xb[2],xb[3]};
        short8 ah, alo;
        split8(xv, ah, alo);
        #pragma unroll
        for (int ntl = 0; ntl < 8; ++ntl){
            int nt = w*8 + ntl;
            size_t f = ((size_t)(nt*4 + ks)*64 + l)*8;
            short8 bh = *(const short8*)(pWi + f);
            short8 bl = *(const short8*)(pWi + 65536 + f);
            acc1[ntl] = __builtin_amdgcn_mfma_f32_16x16x32_bf16(ah,  bh, acc1[ntl], 0,0,0);
            acc1[ntl] = __builtin_amdgcn_mfma_f32_16x16x32_bf16(ah,  bl, acc1[ntl], 0,0,0);
            acc1[ntl] = __builtin_amdgcn_mfma_f32_16x16x32_bf16(alo, bh, acc1[ntl], 0,0,0);
        }
    }
    // gelu -> X1
    #pragma unroll
    for (int ntl = 0; ntl < 8; ++ntl){
        int col = (w*8 + ntl)*16 + l15;
        #pragma unroll
        for (int rr = 0; rr < 4; ++rr){
            int row = lg*4 + rr;
            X1[x1addr(row, col)] = gelu_f(acc1[ntl][rr]);
        }
    }
    __syncthreads();

    // GEMM2: wave w -> ntiles 2w, 2w+1 (cols 32w .. 32w+31)
    f32x4 acc2[2];
    {
        int c0 = (2*w)*16 + l15;
        float v0 = bo[c0], v1 = bo[c0 + 16];
        acc2[0][0]=v0; acc2[0][1]=v0; acc2[0][2]=v0; acc2[0][3]=v0;
        acc2[1][0]=v1; acc2[1][1]=v1; acc2[1][2]=v1; acc2[1][3]=v1;
    }
    #pragma unroll
    for (int ks = 0; ks < 16; ++ks){
        int row = l15;
        int c0 = (ks*32 + lg*8) >> 2;
        f32x4 xa = *(const f32x4*)&X1[row*512 + (( c0    ^ (row&7)) << 2)];
        f32x4 xb = *(const f32x4*)&X1[row*512 + (((c0+1) ^ (row&7)) << 2)];
        float xv[8] = {xa[0],xa[1],xa[2],xa[3],xb[0],xb[1],xb[2],xb[3]};
        short8 ah, alo;
        split8(xv, ah, alo);
        #pragma unroll
        for (int ntl = 0; ntl < 2; ++ntl){
            int nt = 2*w + ntl;
            size_t f = ((size_t)(nt*16 + ks)*64 + l)*8;
            short8 bh = *(const short8*)(pWo + f);
            short8 bl = *(const short8*)(pWo + 65536 + f);
            acc2[ntl] = __builtin_amdgcn_mfma_f32_16x16x32_bf16(ah,  bh, acc2[ntl], 0,0,0);
            acc2[ntl] = __builtin_amdgcn_mfma_f32_16x16x32_bf16(ah,  bl, acc2[ntl], 0,0,0);
            acc2[ntl] = __builtin_amdgcn_mfma_f32_16x16x32_bf16(alo, bh, acc2[ntl], 0,0,0);
        }
    }
    __syncthreads();          // X1 reads done; reuse front of X1 for C
    #pragma unroll
    for (int ntl = 0; ntl < 2; ++ntl){
        int col = (2*w + ntl)*16 + l15;
        #pragma unroll
        for (int rr = 0; rr < 4; ++rr){
            int row = lg*4 + rr;
            X1[xaddr(row, col)] = acc2[ntl][rr];
        }
    }
    __syncthreads();
    if (t < 64){
        const int r = t >> 2, c = t & 3;
        const int gnode = blk*16 + r;
        f32x4 v[8];
        float ls = 0.0f;
        #pragma unroll
        for (int m = 0; m < 8; ++m){
            int col = c*32 + m*4;
            f32x4 y = *(const f32x4*)&X1[xaddr(r, col)];
            f32x4 x = *(const f32x4*)&X0[xaddr(r, col)];
            v[m] = x + y;
            ls += v[m][0]+v[m][1]+v[m][2]+v[m][3];
        }
        ls += __shfl_xor(ls, 1);
        ls += __shfl_xor(ls, 2);
        float mean = ls * (1.0f/128.0f);
        float ls2 = 0.0f;
        #pragma unroll
        for (int m = 0; m < 8; ++m){
            f32x4 d = v[m] - mean;
            ls2 += d[0]*d[0]+d[1]*d[1]+d[2]*d[2]+d[3]*d[3];
        }
        ls2 += __shfl_xor(ls2, 1);
        ls2 += __shfl_xor(ls2, 2);
        float invs = rsqrtf((ls2) * (1.0f/128.0f) + 1e-5f);
        float mv = maskV[gnode];
        #pragma unroll
        for (int m = 0; m < 8; ++m){
            int col = c*32 + m*4;
            f32x4 gg = *(const f32x4*)&g2[col];
            f32x4 bb = *(const f32x4*)&be2[col];
            f32x4 o = ((v[m] - mean)*invs*gg + bb) * mv;
            *(f32x4*)&hVout[(size_t)gnode*Hn + col] = o;
        }
    }
}

// ---------------------------------------------------------------------------
extern "C" void kernel_launch(void* const* d_in, const int* in_sizes, int n_in,
                              void* d_out, int out_size, void* d_ws, size_t ws_size,
                              hipStream_t stream)
{
    const float* h_V  = (const float*)d_in[0];
    const float* h_E  = (const float*)d_in[1];
    const int*   E_idx = (const int*)d_in[2];
    const float* mask_V = (const float*)d_in[3];
    const float* mask_attend = (const float*)d_in[4];
    const float* W1 = (const float*)d_in[5];  const float* b1 = (const float*)d_in[6];
    const float* W2 = (const float*)d_in[7];  const float* b2 = (const float*)d_in[8];
    const float* W3 = (const float*)d_in[9];  const float* b3 = (const float*)d_in[10];
    const float* W11 = (const float*)d_in[11]; const float* b11 = (const float*)d_in[12];
    const float* W12 = (const float*)d_in[13]; const float* b12 = (const float*)d_in[14];
    const float* W13 = (const float*)d_in[15]; const float* b13 = (const float*)d_in[16];
    const float* Wi = (const float*)d_in[17]; const float* bi = (const float*)d_in[18];
    const float* Wo = (const float*)d_in[19]; const float* bo = (const float*)d_in[20];
    const float* g1 = (const float*)d_in[21]; const float* be1 = (const float*)d_in[22];
    const float* g2 = (const float*)d_in[23]; const float* be2 = (const float*)d_in[24];
    const float* g3 = (const float*)d_in[25]; const float* be3 = (const float*)d_in[26];

    const size_t BN = (size_t)Bn * Nn;
    short* pack = (short*)d_ws;                       // 458752 shorts = 896 KB
    float* fws  = (float*)((char*)d_ws + 917504);
    float* Aself = fws;                                // [B*N, H]
    float* Anb   = fws + BN * Hn;                      // [B*N, H]
    float* hVout = (float*)d_out;                      // [B*N, H]
    float* hEout = hVout + BN * Hn;                    // [B*N, K, H]
    float* hVa   = hEout;                              // scratch inside hEout
                                                       // (dead before msg<1>)

    pack_kernel<<<112, 256, 0, stream>>>(W1, W2, W3, W11, W12, W13, Wi, Wo, pack);

    dim3 grid(Bn * Nn), blk(256);
    proj_kernel<<<grid, blk, 0, stream>>>(h_V, W1, b1, Aself, Anb);
    msg_kernel<0><<<grid, blk, 0, stream>>>(h_V, h_E, E_idx, mask_attend,
        Aself, Anb, pack, pack + 32768, pack + 65536, b2, b3, g1, be1, hVa);
    ffn_mfma<<<256, blk, 0, stream>>>(hVa, pack + 196608, pack + 327680,
        bi, bo, g2, be2, mask_V, hVout);
    proj_kernel<<<grid, blk, 0, stream>>>(hVout, W11, b11, Aself, Anb);
    msg_kernel<1><<<grid, blk, 0, stream>>>(nullptr, h_E, E_idx, nullptr,
        Aself, Anb, pack + 98304, pack + 131072, pack + 163840, b12, b13, g3, be3, hEout);
}

// Round 10
// 469.305 us; speedup vs baseline: 2.0568x; 1.0981x over previous
//
#include <hip/hip_runtime.h>
#include <math.h>

// ProteinMPNN layer forward, split-bf16 MFMA, v2: pre-split LDS planes.
// B=2 N=2048 K=48 H=128 FF=512.
// Round-6 PMC: MfmaUtil 15.5%, VALUBusy 68.8% -> VALU-bound on the per-ks
// split8 (duplicated 4x across waves). v2 stores X as hi/lo bf16 PLANES in
// LDS (split once at staging / layer boundary); fragment reads are pure
// ds_read_b128 pairs. Same numerics as round 6 (identical split + MFMA order).

#define Bn 2
#define Nn 2048
#define Kn 48
#define Hn 128
#define FFn 512
#define KH (Kn*Hn)

typedef __attribute__((ext_vector_type(8))) short short8;
typedef __attribute__((ext_vector_type(4))) float f32x4;

__device__ __forceinline__ float gelu_f(float x){
    return 0.5f * x * (1.0f + erff(x * 0.70710678118654752440f));
}

__device__ __forceinline__ unsigned short rne_bf16(float x){
    unsigned int b = __float_as_uint(x);
    return (unsigned short)((b + 0x7fffu + ((b >> 16) & 1u)) >> 16);
}

// split 8 f32 -> hi/lo bf16 (k-contiguous per lane)
__device__ __forceinline__ void split8(const float* x, short8& h, short8& l){
    #pragma unroll
    for (int i = 0; i < 8; ++i){
        unsigned short hu = rne_bf16(x[i]);
        float hf = __uint_as_float(((unsigned int)hu) << 16);
        h[i] = (short)hu;
        l[i] = (short)rne_bf16(x[i] - hf);
    }
}
__device__ __forceinline__ void split1(float x, unsigned short& h, unsigned short& l){
    h = rne_bf16(x);
    float hf = __uint_as_float(((unsigned int)h) << 16);
    l = rne_bf16(x - hf);
}

// f32 [rows][128] swizzled index (for f32 park/LN reuse of the planes)
__device__ __forceinline__ int xaddr(int row, int col){
    int chunk = (col >> 2) ^ (row & 7);
    return row * 128 + chunk * 4 + (col & 3);
}
// bf16 plane [rows][128] swizzled: 16B granule = 8 shorts; chunk = col>>3
__device__ __forceinline__ int paddr(int row, int col){
    return row * 128 + (((col >> 3) ^ (row & 7)) << 3) + (col & 7);
}
// bf16 plane [rows][512]
__device__ __forceinline__ int paddr512(int row, int col){
    return row * 512 + (((col >> 3) ^ (row & 7)) << 3) + (col & 7);
}

// ---------------------------------------------------------------------------
// pack_kernel: W (K x N f32 row-major) -> fragment-ordered hi/lo bf16.
// lf = fs*64+lane, fs = nt*KS + ks; elem i = W[ks*32+(lane>>4)*8+i][nt*16+(lane&15)].
// Regions (short offsets): 6x 128x128 (hi 16384 + lo 16384 each),
// Wi 128x512 @196608, Wo 512x128 @327680. Total 458752 shorts = 896KB.
// ---------------------------------------------------------------------------
__global__ __launch_bounds__(256) void pack_kernel(
    const float* __restrict__ W1, const float* __restrict__ W2,
    const float* __restrict__ W3, const float* __restrict__ W11,
    const float* __restrict__ W12, const float* __restrict__ W13,
    const float* __restrict__ Wi, const float* __restrict__ Wo,
    short* __restrict__ out)
{
    int fid = blockIdx.x * 256 + threadIdx.x;   // grid = 112*256 = 28672 exact
    const float* W; int N, KS, fb, nf; size_t hb;
    if (fid < 12288){
        int r = fid >> 11;
        if      (r == 0) W = W1 + Hn * Hn;
        else if (r == 1) W = W2;
        else if (r == 2) W = W3;
        else if (r == 3) W = W11 + Hn * Hn;
        else if (r == 4) W = W12;
        else             W = W13;
        N = 128; KS = 4; fb = r << 11; nf = 2048; hb = (size_t)r * 32768;
    } else if (fid < 20480){
        W = Wi; N = 512; KS = 4; fb = 12288; nf = 8192; hb = 196608;
    } else {
        W = Wo; N = 128; KS = 16; fb = 20480; nf = 8192; hb = 327680;
    }
    int lf = fid - fb;
    int lane = lf & 63;
    int fs = lf >> 6;
    int ks = fs % KS;
    int nt = fs / KS;
    int k0 = ks * 32 + ((lane >> 4) << 3);
    int col = nt * 16 + (lane & 15);
    float xv[8];
    #pragma unroll
    for (int i = 0; i < 8; ++i) xv[i] = W[(size_t)(k0 + i) * N + col];
    short8 h8, l8;
    split8(xv, h8, l8);
    *(short8*)(out + hb + (size_t)lf * 8) = h8;
    *(short8*)(out + hb + (size_t)nf * 8 + (size_t)lf * 8) = l8;
}

// ---------------------------------------------------------------------------
// proj_kernel: A_self = h_V @ W[0:H] + bias ; A_nb = h_V @ W[2H:3H]
// ---------------------------------------------------------------------------
__global__ __launch_bounds__(256) void proj_kernel(
    const float* __restrict__ hv, const float* __restrict__ W,
    const float* __restrict__ bias,
    float* __restrict__ Aself, float* __restrict__ Anb)
{
    __shared__ float xs[Hn];
    const int t = threadIdx.x;
    const int node = blockIdx.x;
    if (t < Hn) xs[t] = hv[(size_t)node*Hn + t];
    __syncthreads();
    const int o = t & (Hn-1);
    const bool self = (t < Hn);
    const float* Wp = W + (self ? 0 : 2*Hn)*Hn + o;
    float acc = self ? bias[o] : 0.0f;
    #pragma unroll 4
    for (int i = 0; i < Hn; ++i) acc = fmaf(xs[i], Wp[i*Hn], acc);
    if (self) Aself[(size_t)node*Hn + o] = acc;
    else      Anb[(size_t)node*Hn + o]  = acc;
}

// ---------------------------------------------------------------------------
// msg_kernel<EDGE>: one block per node, 4 waves; wave w owns N-cols [32w,32w+32).
// X lives in LDS as hi/lo bf16 planes (pre-split). 3 layers of split-bf16 MFMA.
// EDGE=0: mask+k-sum+LN -> hVa.  EDGE=1: per-edge LN -> hEout.
// ---------------------------------------------------------------------------
template<int EDGE>
__global__ __launch_bounds__(256,4) void msg_kernel(
    const float* __restrict__ hV, const float* __restrict__ hE,
    const int* __restrict__ Eidx, const float* __restrict__ maskA,
    const float* __restrict__ Aself, const float* __restrict__ Anb,
    const short* __restrict__ p1, const short* __restrict__ p2,
    const short* __restrict__ p3,
    const float* __restrict__ b2v, const float* __restrict__ b3v,
    const float* __restrict__ g, const float* __restrict__ be,
    float* __restrict__ out)
{
    __shared__ __align__(16) short Xp[2*KH];   // hi plane [0], lo plane [KH]; 24KB
    __shared__ float dhs[Hn];
    const int t = threadIdx.x;
    const int node = blockIdx.x;
    const int b = node >> 11;
    const int w = t >> 6, l = t & 63;
    const int l15 = l & 15, lg = l >> 4;

    // stage h_E -> split planes (once). 6144 elems, 8/thread/iter, 3 iters.
    const float* hEn = hE + (size_t)node * Kn * Hn;
    #pragma unroll
    for (int it = 0; it < 3; ++it){
        int idx = (t + it*256) * 8;
        int r = idx >> 7, k0 = idx & 127;
        f32x4 a = *(const f32x4*)&hEn[idx];
        f32x4 c = *(const f32x4*)&hEn[idx + 4];
        float xv[8] = {a[0],a[1],a[2],a[3],c[0],c[1],c[2],c[3]};
        short8 h8, l8;
        split8(xv, h8, l8);
        int off = r*128 + (((k0 >> 3) ^ (r & 7)) << 3);
        *(short8*)&Xp[off]      = h8;
        *(short8*)&Xp[KH + off] = l8;
    }

    // layer-1 acc init: Aself (bias folded) + Anb[gather]
    f32x4 acc[3][2];
    {
        int c0 = (2*w)*16 + l15;
        float as0 = Aself[(size_t)node*Hn + c0];
        float as1 = Aself[(size_t)node*Hn + c0 + 16];
        #pragma unroll
        for (int mt = 0; mt < 3; ++mt){
            #pragma unroll
            for (int rr = 0; rr < 4; ++rr){
                int row = mt*16 + lg*4 + rr;
                int idx = Eidx[(size_t)node*Kn + row];
                const float* an = Anb + ((size_t)(b*Nn + idx))*Hn;
                acc[mt][0][rr] = as0 + an[c0];
                acc[mt][1][rr] = as1 + an[c0 + 16];
            }
        }
    }
    __syncthreads();

    #pragma unroll
    for (int L = 0; L < 3; ++L){
        const short* ph = (L == 0) ? p1 : (L == 1) ? p2 : p3;
        if (L > 0){
            const float* bv = (L == 1) ? b2v : b3v;
            int c0 = (2*w)*16 + l15;
            float v0 = bv[c0], v1 = bv[c0 + 16];
            #pragma unroll
            for (int mt = 0; mt < 3; ++mt)
                #pragma unroll
                for (int rr = 0; rr < 4; ++rr){
                    acc[mt][0][rr] = v0; acc[mt][1][rr] = v1;
                }
        }
        #pragma unroll
        for (int ks = 0; ks < 4; ++ks){
            short8 ah[3], al[3];
            #pragma unroll
            for (int mt = 0; mt < 3; ++mt){
                int row = mt*16 + l15;
                int off = row*128 + (((ks*4 + lg) ^ (row & 7)) << 3);
                ah[mt] = *(const short8*)&Xp[off];
                al[mt] = *(const short8*)&Xp[KH + off];
            }
            #pragma unroll
            for (int ntl = 0; ntl < 2; ++ntl){
                int nt = 2*w + ntl;
                size_t f = ((size_t)(nt*4 + ks)*64 + l)*8;
                short8 bh = *(const short8*)(ph + f);
                short8 bl = *(const short8*)(ph + 16384 + f);
                #pragma unroll
                for (int mt = 0; mt < 3; ++mt){
                    acc[mt][ntl] = __builtin_amdgcn_mfma_f32_16x16x32_bf16(ah[mt], bh, acc[mt][ntl], 0,0,0);
                    acc[mt][ntl] = __builtin_amdgcn_mfma_f32_16x16x32_bf16(ah[mt], bl, acc[mt][ntl], 0,0,0);
                    acc[mt][ntl] = __builtin_amdgcn_mfma_f32_16x16x32_bf16(al[mt], bh, acc[mt][ntl], 0,0,0);
                }
            }
        }
        __syncthreads();            // all waves done reading Xp
        if (L < 2){
            #pragma unroll
            for (int mt = 0; mt < 3; ++mt)
                #pragma unroll
                for (int ntl = 0; ntl < 2; ++ntl){
                    int col = (2*w + ntl)*16 + l15;
                    #pragma unroll
                    for (int rr = 0; rr < 4; ++rr){
                        int row = mt*16 + lg*4 + rr;
                        float y = gelu_f(acc[mt][ntl][rr]);
                        unsigned short hu, lu;
                        split1(y, hu, lu);
                        int off = paddr(row, col);
                        Xp[off]      = (short)hu;
                        Xp[KH + off] = (short)lu;
                    }
                }
            __syncthreads();
        }
    }

    if (!EDGE){
        // mask + k-sum; reduce across lane-groups via shfl
        float s0 = 0.f, s1 = 0.f;
        #pragma unroll
        for (int mt = 0; mt < 3; ++mt)
            #pragma unroll
            for (int rr = 0; rr < 4; ++rr){
                int row = mt*16 + lg*4 + rr;
                float m = maskA[(size_t)node*Kn + row];
                s0 = fmaf(m, acc[mt][0][rr], s0);
                s1 = fmaf(m, acc[mt][1][rr], s1);
            }
        s0 += __shfl_xor(s0, 16); s0 += __shfl_xor(s0, 32);
        s1 += __shfl_xor(s1, 16); s1 += __shfl_xor(s1, 32);
        if (lg == 0){
            dhs[2*w*16 + l15]      = s0;
            dhs[2*w*16 + 16 + l15] = s1;
        }
        __syncthreads();
        if (t < 32){
            f32x4 s = *(const f32x4*)&dhs[t*4];
            f32x4 hv = *(const f32x4*)&hV[(size_t)node*Hn + t*4];
            const float inv30 = 1.0f/30.0f;
            f32x4 v = hv + s*inv30;
            float ls = v[0]+v[1]+v[2]+v[3];
            #pragma unroll
            for (int off = 16; off; off >>= 1) ls += __shfl_xor(ls, off);
            float mean = ls * (1.0f/128.0f);
            f32x4 d = v - mean;
            float ls2 = d[0]*d[0]+d[1]*d[1]+d[2]*d[2]+d[3]*d[3];
            #pragma unroll
            for (int off = 16; off; off >>= 1) ls2 += __shfl_xor(ls2, off);
            float invs = rsqrtf(ls2 * (1.0f/128.0f) + 1e-5f);
            f32x4 gg = *(const f32x4*)&g[t*4];
            f32x4 bb = *(const f32x4*)&be[t*4];
            f32x4 o = d*invs*gg + bb;
            *(f32x4*)&out[(size_t)node*Hn + t*4] = o;
        }
    } else {
        // park y3 f32 into the plane memory (reinterpreted), then per-edge LN
        float* Yf = (float*)Xp;      // 48*128 f32 = 24KB = exactly 2 planes
        #pragma unroll
        for (int mt = 0; mt < 3; ++mt)
            #pragma unroll
            for (int ntl = 0; ntl < 2; ++ntl){
                int col = (2*w + ntl)*16 + l15;
                #pragma unroll
                for (int rr = 0; rr < 4; ++rr){
                    int row = mt*16 + lg*4 + rr;
                    Yf[xaddr(row, col)] = acc[mt][ntl][rr];
                }
            }
        __syncthreads();
        if (t < 192){
            const int r = t >> 2, c = t & 3;
            f32x4 v[8];
            float ls = 0.0f;
            #pragma unroll
            for (int m = 0; m < 8; ++m){
                int col = c*32 + m*4;
                f32x4 y = *(const f32x4*)&Yf[xaddr(r, col)];
                f32x4 e = *(const f32x4*)&hEn[r*Hn + col];
                v[m] = y + e;
                ls += v[m][0]+v[m][1]+v[m][2]+v[m][3];
            }
            ls += __shfl_xor(ls, 1);
            ls += __shfl_xor(ls, 2);
            float mean = ls * (1.0f/128.0f);
            float ls2 = 0.0f;
            #pragma unroll
            for (int m = 0; m < 8; ++m){
                f32x4 d = v[m] - mean;
                ls2 += d[0]*d[0]+d[1]*d[1]+d[2]*d[2]+d[3]*d[3];
            }
            ls2 += __shfl_xor(ls2, 1);
            ls2 += __shfl_xor(ls2, 2);
            float invs = rsqrtf(ls2 * (1.0f/128.0f) + 1e-5f);
            float* outR = out + (size_t)node*Kn*Hn + r*Hn;
            #pragma unroll
            for (int m = 0; m < 8; ++m){
                int col = c*32 + m*4;
                f32x4 gg = *(const f32x4*)&g[col];
                f32x4 bb = *(const f32x4*)&be[col];
                f32x4 o = (v[m] - mean)*invs*gg + bb;
                *(f32x4*)&outR[col] = o;
            }
        }
    }
}

// ---------------------------------------------------------------------------
// ffn_mfma: block = 16 nodes. GEMM1 16x128x512, gelu, GEMM2 16x512x128,
// residual (global re-read, L2-hot) + LN + mask_V. Pre-split bf16 planes.
// ---------------------------------------------------------------------------
__global__ __launch_bounds__(256,4) void ffn_mfma(
    const float* __restrict__ hVa,
    const short* __restrict__ pWi, const short* __restrict__ pWo,
    const float* __restrict__ bi, const float* __restrict__ bo,
    const float* __restrict__ g2, const float* __restrict__ be2,
    const float* __restrict__ maskV, float* __restrict__ hVout)
{
    __shared__ __align__(16) short X0p[2*16*128];   // 8 KB (hi @0, lo @2048)
    __shared__ __align__(16) short X1p[2*16*512];   // 32 KB (hi @0, lo @8192)
    const int t = threadIdx.x;
    const int blk = blockIdx.x;
    const int w = t >> 6, l = t & 63;
    const int l15 = l & 15, lg = l >> 4;

    const float* src = hVa + (size_t)blk * 16 * Hn;
    {
        int idx = t * 8;
        int r = idx >> 7, k0 = idx & 127;
        f32x4 a = *(const f32x4*)&src[idx];
        f32x4 c = *(const f32x4*)&src[idx + 4];
        float xv[8] = {a[0],a[1],a[2],a[3],c[0],c[1],c[2],c[3]};
        short8 h8, l8;
        split8(xv, h8, l8);
        int off = r*128 + (((k0 >> 3) ^ (r & 7)) << 3);
        *(short8*)&X0p[off]        = h8;
        *(short8*)&X0p[2048 + off] = l8;
    }
    __syncthreads();

    // GEMM1: wave w -> ntiles w*8 .. w*8+7
    f32x4 acc1[8];
    #pragma unroll
    for (int ntl = 0; ntl < 8; ++ntl){
        float bb = bi[(w*8 + ntl)*16 + l15];
        acc1[ntl][0] = bb; acc1[ntl][1] = bb; acc1[ntl][2] = bb; acc1[ntl][3] = bb;
    }
    #pragma unroll
    for (int ks = 0; ks < 4; ++ks){
        int row = l15;
        int off = row*128 + (((ks*4 + lg) ^ (row & 7)) << 3);
        short8 ah  = *(const short8*)&X0p[off];
        short8 alo = *(const short8*)&X0p[2048 + off];
        #pragma unroll
        for (int ntl = 0; ntl < 8; ++ntl){
            int nt = w*8 + ntl;
            size_t f = ((size_t)(nt*4 + ks)*64 + l)*8;
            short8 bh = *(const short8*)(pWi + f);
            short8 bl = *(const short8*)(pWi + 65536 + f);
            acc1[ntl] = __builtin_amdgcn_mfma_f32_16x16x32_bf16(ah,  bh, acc1[ntl], 0,0,0);
            acc1[ntl] = __builtin_amdgcn_mfma_f32_16x16x32_bf16(ah,  bl, acc1[ntl], 0,0,0);
            acc1[ntl] = __builtin_amdgcn_mfma_f32_16x16x32_bf16(alo, bh, acc1[ntl], 0,0,0);
        }
    }
    // gelu + split -> X1 planes
    #pragma unroll
    for (int ntl = 0; ntl < 8; ++ntl){
        int col = (w*8 + ntl)*16 + l15;
        #pragma unroll
        for (int rr = 0; rr < 4; ++rr){
            int row = lg*4 + rr;
            float y = gelu_f(acc1[ntl][rr]);
            unsigned short hu, lu;
            split1(y, hu, lu);
            int off = paddr512(row, col);
            X1p[off]        = (short)hu;
            X1p[8192 + off] = (short)lu;
        }
    }
    __syncthreads();

    // GEMM2: wave w -> ntiles 2w, 2w+1
    f32x4 acc2[2];
    {
        int c0 = (2*w)*16 + l15;
        float v0 = bo[c0], v1 = bo[c0 + 16];
        acc2[0][0]=v0; acc2[0][1]=v0; acc2[0][2]=v0; acc2[0][3]=v0;
        acc2[1][0]=v1; acc2[1][1]=v1; acc2[1][2]=v1; acc2[1][3]=v1;
    }
    #pragma unroll
    for (int ks = 0; ks < 16; ++ks){
        int row = l15;
        int off = row*512 + (((ks*4 + lg) ^ (row & 7)) << 3);
        short8 ah  = *(const short8*)&X1p[off];
        short8 alo = *(const short8*)&X1p[8192 + off];
        #pragma unroll
        for (int ntl = 0; ntl < 2; ++ntl){
            int nt = 2*w + ntl;
            size_t f = ((size_t)(nt*16 + ks)*64 + l)*8;
            short8 bh = *(const short8*)(pWo + f);
            short8 bl = *(const short8*)(pWo + 65536 + f);
            acc2[ntl] = __builtin_amdgcn_mfma_f32_16x16x32_bf16(ah,  bh, acc2[ntl], 0,0,0);
            acc2[ntl] = __builtin_amdgcn_mfma_f32_16x16x32_bf16(ah,  bl, acc2[ntl], 0,0,0);
            acc2[ntl] = __builtin_amdgcn_mfma_f32_16x16x32_bf16(alo, bh, acc2[ntl], 0,0,0);
        }
    }
    __syncthreads();            // X1 fragment reads done; reuse as f32 C
    float* Cf = (float*)X1p;    // 16*128 f32 = 8KB
    #pragma unroll
    for (int ntl = 0; ntl < 2; ++ntl){
        int col = (2*w + ntl)*16 + l15;
        #pragma unroll
        for (int rr = 0; rr < 4; ++rr){
            int row = lg*4 + rr;
            Cf[xaddr(row, col)] = acc2[ntl][rr];
        }
    }
    __syncthreads();
    if (t < 64){
        const int r = t >> 2, c = t & 3;
        const int gnode = blk*16 + r;
        f32x4 v[8];
        float ls = 0.0f;
        #pragma unroll
        for (int m = 0; m < 8; ++m){
            int col = c*32 + m*4;
            f32x4 y = *(const f32x4*)&Cf[xaddr(r, col)];
            f32x4 x = *(const f32x4*)&src[r*Hn + col];   // residual, L2-hot
            v[m] = x + y;
            ls += v[m][0]+v[m][1]+v[m][2]+v[m][3];
        }
        ls += __shfl_xor(ls, 1);
        ls += __shfl_xor(ls, 2);
        float mean = ls * (1.0f/128.0f);
        float ls2 = 0.0f;
        #pragma unroll
        for (int m = 0; m < 8; ++m){
            f32x4 d = v[m] - mean;
            ls2 += d[0]*d[0]+d[1]*d[1]+d[2]*d[2]+d[3]*d[3];
        }
        ls2 += __shfl_xor(ls2, 1);
        ls2 += __shfl_xor(ls2, 2);
        float invs = rsqrtf(ls2 * (1.0f/128.0f) + 1e-5f);
        float mv = maskV[gnode];
        #pragma unroll
        for (int m = 0; m < 8; ++m){
            int col = c*32 + m*4;
            f32x4 gg = *(const f32x4*)&g2[col];
            f32x4 bb = *(const f32x4*)&be2[col];
            f32x4 o = ((v[m] - mean)*invs*gg + bb) * mv;
            *(f32x4*)&hVout[(size_t)gnode*Hn + col] = o;
        }
    }
}

// ---------------------------------------------------------------------------
extern "C" void kernel_launch(void* const* d_in, const int* in_sizes, int n_in,
                              void* d_out, int out_size, void* d_ws, size_t ws_size,
                              hipStream_t stream)
{
    const float* h_V  = (const float*)d_in[0];
    const float* h_E  = (const float*)d_in[1];
    const int*   E_idx = (const int*)d_in[2];
    const float* mask_V = (const float*)d_in[3];
    const float* mask_attend = (const float*)d_in[4];
    const float* W1 = (const float*)d_in[5];  const float* b1 = (const float*)d_in[6];
    const float* W2 = (const float*)d_in[7];  const float* b2 = (const float*)d_in[8];
    const float* W3 = (const float*)d_in[9];  const float* b3 = (const float*)d_in[10];
    const float* W11 = (const float*)d_in[11]; const float* b11 = (const float*)d_in[12];
    const float* W12 = (const float*)d_in[13]; const float* b12 = (const float*)d_in[14];
    const float* W13 = (const float*)d_in[15]; const float* b13 = (const float*)d_in[16];
    const float* Wi = (const float*)d_in[17]; const float* bi = (const float*)d_in[18];
    const float* Wo = (const float*)d_in[19]; const float* bo = (const float*)d_in[20];
    const float* g1 = (const float*)d_in[21]; const float* be1 = (const float*)d_in[22];
    const float* g2 = (const float*)d_in[23]; const float* be2 = (const float*)d_in[24];
    const float* g3 = (const float*)d_in[25]; const float* be3 = (const float*)d_in[26];

    const size_t BN = (size_t)Bn * Nn;
    short* pack = (short*)d_ws;                       // 458752 shorts = 896 KB
    float* fws  = (float*)((char*)d_ws + 917504);
    float* Aself = fws;                                // [B*N, H]
    float* Anb   = fws + BN * Hn;                      // [B*N, H]
    float* hVout = (float*)d_out;                      // [B*N, H]
    float* hEout = hVout + BN * Hn;                    // [B*N, K, H]
    float* hVa   = hEout;                              // scratch inside hEout
                                                       // (dead before msg<1>)

    pack_kernel<<<112, 256, 0, stream>>>(W1, W2, W3, W11, W12, W13, Wi, Wo, pack);

    dim3 grid(Bn * Nn), blk(256);
    proj_kernel<<<grid, blk, 0, stream>>>(h_V, W1, b1, Aself, Anb);
    msg_kernel<0><<<grid, blk, 0, stream>>>(h_V, h_E, E_idx, mask_attend,
        Aself, Anb, pack, pack + 32768, pack + 65536, b2, b3, g1, be1, hVa);
    ffn_mfma<<<256, blk, 0, stream>>>(hVa, pack + 196608, pack + 327680,
        bi, bo, g2, be2, mask_V, hVout);
    proj_kernel<<<grid, blk, 0, stream>>>(hVout, W11, b11, Aself, Anb);
    msg_kernel<1><<<grid, blk, 0, stream>>>(nullptr, h_E, E_idx, nullptr,
        Aself, Anb, pack + 98304, pack + 131072, pack + 163840, b12, b13, g3, be3, hEout);
}